// Round 7
// baseline (620.461 us; speedup 1.0000x reference)
//
#include <hip/hip_runtime.h>
#include <hip/hip_bf16.h>
#include <hip/hip_fp16.h>

#define NN 100000
#define NE 1600000
#define FIN 128
#define HD 64
#define NB_SCAN 391    // ceil(NN/256)
#define BSH 9          // bucket covers 512 dest nodes
#define NBUCK 196      // ceil(NN/512)
#define BCAP 10240     // per-bucket staging cap (mean 8163, sigma 128 -> +16 sigma)
#define CHUNK 4096     // edges per stage-1 block
#define NCHUNK 391     // ceil(NE/CHUNK)
#define EBLOCKS 2048   // edge-kernel blocks (8192 waves)

typedef unsigned int uint32;

// ---------------- stage 1: block-level counting sort into 196 buckets ----------------
__global__ void __launch_bounds__(256) k_part(const int* __restrict__ row,
                                              const int* __restrict__ col,
                                              int* __restrict__ bcnt,
                                              uint32* __restrict__ staged){
    __shared__ int hist[NBUCK];
    __shared__ int base[NBUCK];
    int t = threadIdx.x;
    int e0 = blockIdx.x * CHUNK;
    int e1 = min(e0 + CHUNK, NE);
    for(int i = t; i < NBUCK; i += 256) hist[i] = 0;
    __syncthreads();
    for(int e = e0 + t; e < e1; e += 256)
        atomicAdd(&hist[col[e] >> BSH], 1);
    __syncthreads();
    for(int i = t; i < NBUCK; i += 256){
        int c = hist[i];
        base[i] = (c > 0) ? atomicAdd(&bcnt[i], c) : 0;   // one global atomic per (block,bucket)
        hist[i] = 0;                                       // reuse as cursor
    }
    __syncthreads();
    for(int e = e0 + t; e < e1; e += 256){
        int c = col[e], r = row[e];
        int b = c >> BSH;
        int pos = base[b] + atomicAdd(&hist[b], 1);
        if(pos < BCAP)
            staged[(size_t)b*BCAP + pos] = ((uint32)r << BSH) | (uint32)(c & 511);
    }
}

// ---------------- stage 2a: per-bucket LDS histogram -> deg ----------------
__global__ void __launch_bounds__(256) k_hist(const int* __restrict__ bcnt,
                                              const uint32* __restrict__ staged,
                                              int* __restrict__ deg){
    __shared__ int h[512];
    int b = blockIdx.x, t = threadIdx.x;
    for(int i = t; i < 512; i += 256) h[i] = 0;
    __syncthreads();
    int cnt = min(bcnt[b], BCAP);
    const uint32* st = staged + (size_t)b*BCAP;
    for(int i = t; i < cnt; i += 256) atomicAdd(&h[st[i] & 511u], 1);
    __syncthreads();
    for(int i = t; i < 512; i += 256){
        int n = b*512 + i;
        if(n < NN) deg[n] = h[i];
    }
}

// ---------------- scan chain (deg -> starts, dinv) ----------------
__global__ void k_bsum(const int* __restrict__ deg, int* __restrict__ bsum){
    __shared__ int r[256];
    int t = threadIdx.x; int i = blockIdx.x*256 + t;
    r[t] = (i < NN) ? deg[i] : 0;
    __syncthreads();
    for(int off=128; off>0; off>>=1){ if(t<off) r[t]+=r[t+off]; __syncthreads(); }
    if(t==0) bsum[blockIdx.x] = r[0];
}

__global__ void k_top(int* __restrict__ bsum){
    __shared__ int s[512];
    int t = threadIdx.x;
    int v = (t < NB_SCAN) ? bsum[t] : 0;
    s[t] = v; __syncthreads();
    for(int off=1; off<512; off<<=1){
        int a = (t>=off)? s[t-off] : 0;
        __syncthreads();
        s[t] += a;
        __syncthreads();
    }
    if(t < NB_SCAN) bsum[t] = s[t] - v;   // exclusive scan of block sums
}

__global__ void k_scan(const int* __restrict__ deg, const int* __restrict__ bsum,
                       int* __restrict__ starts, float* __restrict__ dinv){
    __shared__ int s[256];
    int t = threadIdx.x; int i = blockIdx.x*256 + t;
    int d = (i<NN)? deg[i] : 0;
    s[t] = d; __syncthreads();
    for(int off=1; off<256; off<<=1){
        int a = (t>=off)? s[t-off] : 0;
        __syncthreads();
        s[t] += a;
        __syncthreads();
    }
    if(i < NN){
        starts[i] = bsum[blockIdx.x] + s[t] - d;   // exclusive
        dinv[i] = rsqrtf((float)(d + 1));          // +1 self-loop
    }
}

// ---------------- stage 2b: per-bucket LDS scatter, coalesced csr write ----------------
__global__ void __launch_bounds__(256) k_fill2(const int* __restrict__ bcnt,
                                               const uint32* __restrict__ staged,
                                               const int* __restrict__ starts,
                                               int* __restrict__ csr){
    __shared__ int cur[512];
    __shared__ int lcsr[BCAP];
    int b = blockIdx.x, t = threadIdx.x;
    int n0 = b*512;
    int base = starts[n0];
    for(int i = t; i < 512; i += 256){
        int n = n0 + i;
        cur[i] = (n < NN) ? starts[n] - base : 0;
    }
    __syncthreads();
    int cnt = min(bcnt[b], BCAP);
    const uint32* st = staged + (size_t)b*BCAP;
    for(int i = t; i < cnt; i += 256){
        uint32 u = st[i];
        int p = atomicAdd(&cur[u & 511u], 1);
        lcsr[p] = (int)(u >> BSH);
    }
    __syncthreads();
    for(int i = t; i < cnt; i += 256) csr[base + i] = lcsr[i];
}

// ---------------- BN constant folding ----------------
__global__ void k_const(const float* __restrict__ encB, const float* __restrict__ encG,
                        const float* __restrict__ encBe, const float* __restrict__ encM,
                        const float* __restrict__ encV,
                        const float* __restrict__ ep1b, const float* __restrict__ epG,
                        const float* __restrict__ epBe, const float* __restrict__ epM,
                        const float* __restrict__ epV,
                        float* __restrict__ foldEnc, float* __restrict__ foldPre){
    int j = threadIdx.x;
    if(j < 64){
        float s = encG[j]*rsqrtf(encV[j]+1e-5f);
        foldEnc[j]      = s;
        foldEnc[64+j]   = (encB[j]-encM[j])*s + encBe[j];
        float sp = epG[j]*rsqrtf(epV[j]+1e-5f);
        foldPre[j]      = sp;
        foldPre[64+j]   = sp;
        foldPre[128+j]  = sp*(ep1b[j]-epM[j]) + epBe[j];
        foldPre[192+j]  = 0.f;
    }
}

// ---------------- generic GEMV: thread-per-node, W staged in LDS ----------------
// PREMAP: W source is ep1W [128,64]; logical W[k][j] = j<64 ? ep1W[k][j] : ep1W[64+k][j-64]
template<int K, int JB, bool PREMAP, bool FOLD, bool RELU, bool OH>
__global__ void __launch_bounds__(256) k_gemv(const float* __restrict__ in,
                                              const float* __restrict__ W,
                                              const float* __restrict__ fold,
                                              void* __restrict__ outv){
    __shared__ float Ws[K*JB*64];
    __shared__ float Fs[2*JB*64];
    const int J = JB*64;
    for(int idx = threadIdx.x; idx < K*J; idx += 256){
        if(PREMAP){
            int k = idx / J, j = idx % J;   // J=128 here
            Ws[idx] = (j < 64) ? W[k*64 + j] : W[(64+k)*64 + (j-64)];
        } else {
            Ws[idx] = W[idx];
        }
    }
    if(FOLD){
        for(int idx = threadIdx.x; idx < 2*J; idx += 256) Fs[idx] = fold[idx];
    }
    __syncthreads();
    int n = blockIdx.x*256 + threadIdx.x;
    if(n >= NN) return;
    const float4* x4 = (const float4*)(in + (size_t)n*K);
    for(int jb = 0; jb < JB; jb++){
        float acc[64];
        #pragma unroll
        for(int j = 0; j < 64; j++) acc[j] = 0.f;
        for(int k4 = 0; k4 < K/4; k4++){
            float4 xv = x4[k4];
            #pragma unroll
            for(int kk = 0; kk < 4; kk++){
                float xs_ = (kk==0)?xv.x:(kk==1)?xv.y:(kk==2)?xv.z:xv.w;
                const float4* wrow = (const float4*)&Ws[(k4*4+kk)*J + jb*64];
                #pragma unroll
                for(int j4 = 0; j4 < 16; j4++){
                    float4 w = wrow[j4];
                    acc[4*j4+0] = fmaf(xs_, w.x, acc[4*j4+0]);
                    acc[4*j4+1] = fmaf(xs_, w.y, acc[4*j4+1]);
                    acc[4*j4+2] = fmaf(xs_, w.z, acc[4*j4+2]);
                    acc[4*j4+3] = fmaf(xs_, w.w, acc[4*j4+3]);
                }
            }
        }
        #pragma unroll
        for(int j4 = 0; j4 < 16; j4++){
            float vv[4];
            #pragma unroll
            for(int c = 0; c < 4; c++){
                int j = 4*j4 + c;
                float t = acc[j];
                if(FOLD) t = t*Fs[jb*64+j] + Fs[J + jb*64 + j];
                if(RELU) t = fmaxf(t, 0.f);
                vv[c] = t;
            }
            if(OH){
                ushort4 u;
                u.x = __half_as_ushort(__float2half_rn(vv[0]));
                u.y = __half_as_ushort(__float2half_rn(vv[1]));
                u.z = __half_as_ushort(__float2half_rn(vv[2]));
                u.w = __half_as_ushort(__float2half_rn(vv[3]));
                ((ushort4*)((unsigned short*)outv + (size_t)n*J + jb*64))[j4] = u;
            } else {
                float4 v;
                v.x = vv[0]; v.y = vv[1]; v.z = vv[2]; v.w = vv[3];
                ((float4*)((float*)outv + (size_t)n*J + jb*64))[j4] = v;
            }
        }
    }
}

// ---------------- GCN aggregation (fp16 hw): relu(sum_in + self + b) ----------------
__global__ void __launch_bounds__(256) k_agg(const __half* __restrict__ hw,
                                             const int* __restrict__ starts,
                                             const int* __restrict__ deg,
                                             const int* __restrict__ csr,
                                             const float* __restrict__ dinv,
                                             const float* __restrict__ bias,
                                             float* __restrict__ out){
    int t = threadIdx.x, w = t>>6, f = t&63;
    int n = blockIdx.x*4 + w;
    int s = starts[n], d = deg[n];
    float acc = 0.f;
    int i = 0;
    for(; i+7 < d; i += 8){                 // 8-way unroll for outstanding gathers
        int r0 = csr[s+i],   r1 = csr[s+i+1];
        int r2 = csr[s+i+2], r3 = csr[s+i+3];
        int r4 = csr[s+i+4], r5 = csr[s+i+5];
        int r6 = csr[s+i+6], r7 = csr[s+i+7];
        float v0 = __half2float(hw[(size_t)r0*64 + f]);
        float v1 = __half2float(hw[(size_t)r1*64 + f]);
        float v2 = __half2float(hw[(size_t)r2*64 + f]);
        float v3 = __half2float(hw[(size_t)r3*64 + f]);
        float v4 = __half2float(hw[(size_t)r4*64 + f]);
        float v5 = __half2float(hw[(size_t)r5*64 + f]);
        float v6 = __half2float(hw[(size_t)r6*64 + f]);
        float v7 = __half2float(hw[(size_t)r7*64 + f]);
        acc = fmaf(v0, dinv[r0], acc);
        acc = fmaf(v1, dinv[r1], acc);
        acc = fmaf(v2, dinv[r2], acc);
        acc = fmaf(v3, dinv[r3], acc);
        acc = fmaf(v4, dinv[r4], acc);
        acc = fmaf(v5, dinv[r5], acc);
        acc = fmaf(v6, dinv[r6], acc);
        acc = fmaf(v7, dinv[r7], acc);
    }
    for(; i < d; i++){
        int r0 = csr[s+i];
        acc = fmaf(__half2float(hw[(size_t)r0*64 + f]), dinv[r0], acc);
    }
    float dn = dinv[n];
    float self = __half2float(hw[(size_t)n*64 + f]);
    float v = acc*dn + self*dn*dn + bias[f];
    out[(size_t)n*64 + f] = fmaxf(v, 0.f);
}

// ---------------- edge predictor: wave-cooperative, one edge per wave-step ----------------
// pre[n] = [A(64 fp16) | B(64 fp16)] = 256 B. Lane j loads dword j of pre[j<32 ? row : col]:
// j<32 -> A-half dword j of pre[r]; j>=32 -> B-half dword j of pre[c]. shfl_xor(32) exchanges
// partner dwords; each lane's partial covers features {2*(j&31), 2*(j&31)+1}; lanes 0-31 and
// 32-63 compute identical partials, so a 5-step butterfly over the 32-group sums to z.
__global__ void __launch_bounds__(256) k_edge3(const __half* __restrict__ pre,
                                               const int* __restrict__ row,
                                               const int* __restrict__ col,
                                               const float* __restrict__ w2,
                                               const float* __restrict__ b2,
                                               float* __restrict__ out){
    int t = threadIdx.x, w = t>>6, j = t&63;
    int wave = blockIdx.x*4 + w;
    const int NW = EBLOCKS*4;
    const int C = (NE + NW - 1)/NW;       // contiguous chunk per wave -> sequential out writes
    int e0 = wave*C, e1 = min(e0+C, NE);
    int jj = j & 31;
    float w2a = w2[2*jj], w2b = w2[2*jj+1];
    float b2v = b2[0];
    int e = e0;
    for(; e+1 < e1; e += 2){
        int sel0 = (j<32) ? row[e]   : col[e];
        int sel1 = (j<32) ? row[e+1] : col[e+1];
        uint32 u0 = *(const uint32*)((const unsigned short*)pre + (size_t)sel0*128 + 2*j);
        uint32 u1 = *(const uint32*)((const unsigned short*)pre + (size_t)sel1*128 + 2*j);
        uint32 v0 = (uint32)__shfl_xor((int)u0, 32, 64);
        uint32 v1 = (uint32)__shfl_xor((int)u1, 32, 64);
        float2 a0 = __half22float2(*(const __half2*)&u0);
        float2 b0 = __half22float2(*(const __half2*)&v0);
        float2 a1 = __half22float2(*(const __half2*)&u1);
        float2 b1 = __half22float2(*(const __half2*)&v1);
        float p0 = fmaxf(a0.x+b0.x,0.f)*w2a + fmaxf(a0.y+b0.y,0.f)*w2b;
        float p1 = fmaxf(a1.x+b1.x,0.f)*w2a + fmaxf(a1.y+b1.y,0.f)*w2b;
        #pragma unroll
        for(int off=1; off<32; off<<=1){
            p0 += __shfl_xor(p0, off, 64);
            p1 += __shfl_xor(p1, off, 64);
        }
        if(j == 0){
            out[e]   = 1.f/(1.f+__expf(-(p0+b2v)));
            out[e+1] = 1.f/(1.f+__expf(-(p1+b2v)));
        }
    }
    if(e < e1){
        int sel0 = (j<32) ? row[e] : col[e];
        uint32 u0 = *(const uint32*)((const unsigned short*)pre + (size_t)sel0*128 + 2*j);
        uint32 v0 = (uint32)__shfl_xor((int)u0, 32, 64);
        float2 a0 = __half22float2(*(const __half2*)&u0);
        float2 b0 = __half22float2(*(const __half2*)&v0);
        float p0 = fmaxf(a0.x+b0.x,0.f)*w2a + fmaxf(a0.y+b0.y,0.f)*w2b;
        #pragma unroll
        for(int off=1; off<32; off<<=1) p0 += __shfl_xor(p0, off, 64);
        if(j == 0) out[e] = 1.f/(1.f+__expf(-(p0+b2v)));
    }
}

// ---------------- launch ----------------

extern "C" void kernel_launch(void* const* d_in, const int* in_sizes, int n_in,
                              void* d_out, int out_size, void* d_ws, size_t ws_size,
                              hipStream_t stream){
    const float* x   = (const float*)d_in[0];
    const int* ei    = (const int*)d_in[1];
    const int* row   = ei;
    const int* col   = ei + NE;
    const float* encW = (const float*)d_in[2],  *encB = (const float*)d_in[3];
    const float* encG = (const float*)d_in[4],  *encBe= (const float*)d_in[5];
    const float* encM = (const float*)d_in[6],  *encV = (const float*)d_in[7];
    const float* c1W  = (const float*)d_in[8],  *c1b  = (const float*)d_in[9];
    const float* c2W  = (const float*)d_in[10], *c2b  = (const float*)d_in[11];
    const float* ep1W = (const float*)d_in[12], *ep1b = (const float*)d_in[13];
    const float* epG  = (const float*)d_in[14], *epBe = (const float*)d_in[15];
    const float* epM  = (const float*)d_in[16], *epV  = (const float*)d_in[17];
    const float* ep2W = (const float*)d_in[18], *ep2b = (const float*)d_in[19];

    char* wsc = (char*)d_ws;
    size_t o = 0;
    auto alloc = [&](size_t bytes)->void*{
        void* p = wsc + o; o += (bytes + 255) & ~(size_t)255; return p;
    };
    int*    deg     = (int*)   alloc((size_t)NN*4);
    int*    starts  = (int*)   alloc((size_t)NN*4);
    int*    bsum    = (int*)   alloc(1024*4);
    int*    bcnt    = (int*)   alloc((size_t)NBUCK*4);
    int*    csr     = (int*)   alloc((size_t)NE*4);
    uint32* staged  = (uint32*)alloc((size_t)NBUCK*BCAP*4);   // 8.0 MB
    float*  dinv    = (float*) alloc((size_t)NN*4);
    float*  foldEnc = (float*) alloc(128*4);
    float*  foldPre = (float*) alloc(256*4);
    float*  bufA    = (float*) alloc((size_t)NN*64*4);        // fp32 h buffer (25.6 MB)
    __half* bufB    = (__half*)alloc((size_t)NN*64*2);        // fp16 hw buffer (12.8 MB)
    // pre[N,128] fp16 (25.6 MB) aliases bufA (dead after conv2 gemv)
    __half* preh    = (__half*)bufA;
    // total ~54 MB of d_ws

    float* outp = (float*)d_out;               // [NN*64] node emb | [NE] edge preds
    float* node_out = outp;
    float* edge_out = outp + (size_t)NN*64;

    hipMemsetAsync(bcnt, 0, (size_t)NBUCK*4, stream);
    k_part <<<NCHUNK,  256, 0, stream>>>(row, col, bcnt, staged);
    k_hist <<<NBUCK,   256, 0, stream>>>(bcnt, staged, deg);
    k_bsum <<<NB_SCAN, 256, 0, stream>>>(deg, bsum);
    k_top  <<<1,       512, 0, stream>>>(bsum);
    k_scan <<<NB_SCAN, 256, 0, stream>>>(deg, bsum, starts, dinv);
    k_fill2<<<NBUCK,   256, 0, stream>>>(bcnt, staged, starts, csr);
    k_const<<<1, 64, 0, stream>>>(encB, encG, encBe, encM, encV,
                                  ep1b, epG, epBe, epM, epV, foldEnc, foldPre);

    // encoder: relu(bn(x @ encW + b)) -> fp32 bufA
    k_gemv<128,1,false,true,true,false><<<NB_SCAN, 256, 0, stream>>>(x, encW, foldEnc, bufA);

    // conv1: hw fp16 -> aggregate fp32
    k_gemv<64,1,false,false,false,true><<<NB_SCAN, 256, 0, stream>>>(bufA, c1W, nullptr, bufB);
    k_agg  <<<NN/4, 256, 0, stream>>>(bufB, starts, deg, csr, dinv, c1b, bufA);

    // conv2
    k_gemv<64,1,false,false,false,true><<<NB_SCAN, 256, 0, stream>>>(bufA, c2W, nullptr, bufB);
    k_agg  <<<NN/4, 256, 0, stream>>>(bufB, starts, deg, csr, dinv, c2b, node_out);

    // edge predictor precompute -> fp16 pre [A|B] interleaved
    k_gemv<64,2,true,true,false,true><<<NB_SCAN, 256, 0, stream>>>(node_out, ep1W, foldPre, preh);

    // per-edge: sigmoid(sum relu(preA[r]+preB[c])*w2 + b2), wave-cooperative
    k_edge3<<<EBLOCKS, 256, 0, stream>>>(preh, row, col, ep2W, ep2b, edge_out);
}

// Round 9
// 525.370 us; speedup vs baseline: 1.1810x; 1.1810x over previous
//
#include <hip/hip_runtime.h>
#include <hip/hip_bf16.h>
#include <hip/hip_fp16.h>

#define NN 100000
#define NE 1600000
#define FIN 128
#define HD 64
#define NB_SCAN 391    // ceil(NN/256)
#define BSH 9          // bucket covers 512 dest nodes
#define NBUCK 196      // ceil(NN/512)
#define BCAP 10240     // per-bucket staging cap (mean 8163, sigma 128 -> +16 sigma)
#define CHUNK 4096     // edges per stage-1 block
#define NCHUNK 391     // ceil(NE/CHUNK)
#define EBLOCKS 2048   // edge-kernel blocks (8192 waves)

typedef unsigned int uint32;

// ---------------- stage 1: block-level counting sort into 196 buckets ----------------
__global__ void __launch_bounds__(256) k_part(const int* __restrict__ row,
                                              const int* __restrict__ col,
                                              int* __restrict__ bcnt,
                                              uint32* __restrict__ staged){
    __shared__ int hist[NBUCK];
    __shared__ int base[NBUCK];
    int t = threadIdx.x;
    int e0 = blockIdx.x * CHUNK;
    int e1 = min(e0 + CHUNK, NE);
    for(int i = t; i < NBUCK; i += 256) hist[i] = 0;
    __syncthreads();
    for(int e = e0 + t; e < e1; e += 256)
        atomicAdd(&hist[col[e] >> BSH], 1);
    __syncthreads();
    for(int i = t; i < NBUCK; i += 256){
        int c = hist[i];
        base[i] = (c > 0) ? atomicAdd(&bcnt[i], c) : 0;   // one global atomic per (block,bucket)
        hist[i] = 0;                                       // reuse as cursor
    }
    __syncthreads();
    for(int e = e0 + t; e < e1; e += 256){
        int c = col[e], r = row[e];
        int b = c >> BSH;
        int pos = base[b] + atomicAdd(&hist[b], 1);
        if(pos < BCAP)
            staged[(size_t)b*BCAP + pos] = ((uint32)r << BSH) | (uint32)(c & 511);
    }
}

// ---------------- stage 2a: per-bucket LDS histogram -> deg ----------------
__global__ void __launch_bounds__(256) k_hist(const int* __restrict__ bcnt,
                                              const uint32* __restrict__ staged,
                                              int* __restrict__ deg){
    __shared__ int h[512];
    int b = blockIdx.x, t = threadIdx.x;
    for(int i = t; i < 512; i += 256) h[i] = 0;
    __syncthreads();
    int cnt = min(bcnt[b], BCAP);
    const uint32* st = staged + (size_t)b*BCAP;
    for(int i = t; i < cnt; i += 256) atomicAdd(&h[st[i] & 511u], 1);
    __syncthreads();
    for(int i = t; i < 512; i += 256){
        int n = b*512 + i;
        if(n < NN) deg[n] = h[i];
    }
}

// ---------------- scan chain (deg -> starts, dinv) ----------------
__global__ void k_bsum(const int* __restrict__ deg, int* __restrict__ bsum){
    __shared__ int r[256];
    int t = threadIdx.x; int i = blockIdx.x*256 + t;
    r[t] = (i < NN) ? deg[i] : 0;
    __syncthreads();
    for(int off=128; off>0; off>>=1){ if(t<off) r[t]+=r[t+off]; __syncthreads(); }
    if(t==0) bsum[blockIdx.x] = r[0];
}

__global__ void k_top(int* __restrict__ bsum){
    __shared__ int s[512];
    int t = threadIdx.x;
    int v = (t < NB_SCAN) ? bsum[t] : 0;
    s[t] = v; __syncthreads();
    for(int off=1; off<512; off<<=1){
        int a = (t>=off)? s[t-off] : 0;
        __syncthreads();
        s[t] += a;
        __syncthreads();
    }
    if(t < NB_SCAN) bsum[t] = s[t] - v;   // exclusive scan of block sums
}

__global__ void k_scan(const int* __restrict__ deg, const int* __restrict__ bsum,
                       int* __restrict__ starts, float* __restrict__ dinv){
    __shared__ int s[256];
    int t = threadIdx.x; int i = blockIdx.x*256 + t;
    int d = (i<NN)? deg[i] : 0;
    s[t] = d; __syncthreads();
    for(int off=1; off<256; off<<=1){
        int a = (t>=off)? s[t-off] : 0;
        __syncthreads();
        s[t] += a;
        __syncthreads();
    }
    if(i < NN){
        starts[i] = bsum[blockIdx.x] + s[t] - d;   // exclusive
        dinv[i] = rsqrtf((float)(d + 1));          // +1 self-loop
    }
}

// ---------------- stage 2b: per-bucket LDS scatter, coalesced csr write ----------------
__global__ void __launch_bounds__(256) k_fill2(const int* __restrict__ bcnt,
                                               const uint32* __restrict__ staged,
                                               const int* __restrict__ starts,
                                               int* __restrict__ csr){
    __shared__ int cur[512];
    __shared__ int lcsr[BCAP];
    int b = blockIdx.x, t = threadIdx.x;
    int n0 = b*512;
    int base = starts[n0];
    for(int i = t; i < 512; i += 256){
        int n = n0 + i;
        cur[i] = (n < NN) ? starts[n] - base : 0;
    }
    __syncthreads();
    int cnt = min(bcnt[b], BCAP);
    const uint32* st = staged + (size_t)b*BCAP;
    for(int i = t; i < cnt; i += 256){
        uint32 u = st[i];
        int p = atomicAdd(&cur[u & 511u], 1);
        lcsr[p] = (int)(u >> BSH);
    }
    __syncthreads();
    for(int i = t; i < cnt; i += 256) csr[base + i] = lcsr[i];
}

// ---------------- BN constant folding ----------------
__global__ void k_const(const float* __restrict__ encB, const float* __restrict__ encG,
                        const float* __restrict__ encBe, const float* __restrict__ encM,
                        const float* __restrict__ encV,
                        const float* __restrict__ ep1b, const float* __restrict__ epG,
                        const float* __restrict__ epBe, const float* __restrict__ epM,
                        const float* __restrict__ epV,
                        float* __restrict__ foldEnc, float* __restrict__ foldPre){
    int j = threadIdx.x;
    if(j < 64){
        float s = encG[j]*rsqrtf(encV[j]+1e-5f);
        foldEnc[j]      = s;
        foldEnc[64+j]   = (encB[j]-encM[j])*s + encBe[j];
        float sp = epG[j]*rsqrtf(epV[j]+1e-5f);
        foldPre[j]      = sp;
        foldPre[64+j]   = sp;
        foldPre[128+j]  = sp*(ep1b[j]-epM[j]) + epBe[j];
        foldPre[192+j]  = 0.f;
    }
}

// ---------------- generic GEMV: thread-per-node, W staged in LDS ----------------
// PREMAP: W source is ep1W [128,64]; logical W[k][j] = j<64 ? ep1W[k][j] : ep1W[64+k][j-64]
// SCALE: multiply output row by rowscale[n] (used to fold dinv into hw')
template<int K, int JB, bool PREMAP, bool FOLD, bool RELU, bool OH, bool SCALE>
__global__ void __launch_bounds__(256) k_gemv(const float* __restrict__ in,
                                              const float* __restrict__ W,
                                              const float* __restrict__ fold,
                                              const float* __restrict__ rowscale,
                                              void* __restrict__ outv){
    __shared__ float Ws[K*JB*64];
    __shared__ float Fs[2*JB*64];
    const int J = JB*64;
    for(int idx = threadIdx.x; idx < K*J; idx += 256){
        if(PREMAP){
            int k = idx / J, j = idx % J;   // J=128 here
            Ws[idx] = (j < 64) ? W[k*64 + j] : W[(64+k)*64 + (j-64)];
        } else {
            Ws[idx] = W[idx];
        }
    }
    if(FOLD){
        for(int idx = threadIdx.x; idx < 2*J; idx += 256) Fs[idx] = fold[idx];
    }
    __syncthreads();
    int n = blockIdx.x*256 + threadIdx.x;
    if(n >= NN) return;
    float rs = SCALE ? rowscale[n] : 1.f;
    const float4* x4 = (const float4*)(in + (size_t)n*K);
    for(int jb = 0; jb < JB; jb++){
        float acc[64];
        #pragma unroll
        for(int j = 0; j < 64; j++) acc[j] = 0.f;
        for(int k4 = 0; k4 < K/4; k4++){
            float4 xv = x4[k4];
            #pragma unroll
            for(int kk = 0; kk < 4; kk++){
                float xs_ = (kk==0)?xv.x:(kk==1)?xv.y:(kk==2)?xv.z:xv.w;
                const float4* wrow = (const float4*)&Ws[(k4*4+kk)*J + jb*64];
                #pragma unroll
                for(int j4 = 0; j4 < 16; j4++){
                    float4 w = wrow[j4];
                    acc[4*j4+0] = fmaf(xs_, w.x, acc[4*j4+0]);
                    acc[4*j4+1] = fmaf(xs_, w.y, acc[4*j4+1]);
                    acc[4*j4+2] = fmaf(xs_, w.z, acc[4*j4+2]);
                    acc[4*j4+3] = fmaf(xs_, w.w, acc[4*j4+3]);
                }
            }
        }
        #pragma unroll
        for(int j4 = 0; j4 < 16; j4++){
            float vv[4];
            #pragma unroll
            for(int c = 0; c < 4; c++){
                int j = 4*j4 + c;
                float t = acc[j];
                if(FOLD) t = t*Fs[jb*64+j] + Fs[J + jb*64 + j];
                if(RELU) t = fmaxf(t, 0.f);
                if(SCALE) t *= rs;
                vv[c] = t;
            }
            if(OH){
                ushort4 u;
                u.x = __half_as_ushort(__float2half_rn(vv[0]));
                u.y = __half_as_ushort(__float2half_rn(vv[1]));
                u.z = __half_as_ushort(__float2half_rn(vv[2]));
                u.w = __half_as_ushort(__float2half_rn(vv[3]));
                ((ushort4*)((unsigned short*)outv + (size_t)n*J + jb*64))[j4] = u;
            } else {
                float4 v;
                v.x = vv[0]; v.y = vv[1]; v.z = vv[2]; v.w = vv[3];
                ((float4*)((float*)outv + (size_t)n*J + jb*64))[j4] = v;
            }
        }
    }
}

// ---------------- GCN aggregation (pre-scaled fp16 hw'): relu(dn*(sum + self) + b) ----------------
__global__ void __launch_bounds__(256) k_agg2(const __half* __restrict__ hws,
                                              const int* __restrict__ starts,
                                              const int* __restrict__ deg,
                                              const int* __restrict__ csr,
                                              const float* __restrict__ dinv,
                                              const float* __restrict__ bias,
                                              float* __restrict__ out){
    int t = threadIdx.x, w = t>>6, f = t&63;
    int n = blockIdx.x*4 + w;
    int s = __builtin_amdgcn_readfirstlane(starts[n]);
    int d = __builtin_amdgcn_readfirstlane(deg[n]);
    float acc = 0.f;
    int i = 0;
    for(; i+7 < d; i += 8){                 // 8-way unroll for outstanding gathers
        int r0 = csr[s+i],   r1 = csr[s+i+1];
        int r2 = csr[s+i+2], r3 = csr[s+i+3];
        int r4 = csr[s+i+4], r5 = csr[s+i+5];
        int r6 = csr[s+i+6], r7 = csr[s+i+7];
        float v0 = __half2float(hws[(size_t)r0*64 + f]);
        float v1 = __half2float(hws[(size_t)r1*64 + f]);
        float v2 = __half2float(hws[(size_t)r2*64 + f]);
        float v3 = __half2float(hws[(size_t)r3*64 + f]);
        float v4 = __half2float(hws[(size_t)r4*64 + f]);
        float v5 = __half2float(hws[(size_t)r5*64 + f]);
        float v6 = __half2float(hws[(size_t)r6*64 + f]);
        float v7 = __half2float(hws[(size_t)r7*64 + f]);
        acc += v0 + v1 + v2 + v3 + v4 + v5 + v6 + v7;
    }
    for(; i < d; i++){
        int r0 = csr[s+i];
        acc += __half2float(hws[(size_t)r0*64 + f]);
    }
    float dn = dinv[n];
    float self = __half2float(hws[(size_t)n*64 + f]);
    float v = (acc + self)*dn + bias[f];
    out[(size_t)n*64 + f] = fmaxf(v, 0.f);
}

// ---------------- edge predictor: octet-cooperative ----------------
// 8 lanes per edge. Lane p of an octet loads dwordx4 p of pre[r]'s A-half and of
// pre[c]'s B-half (contiguous fully-used 128 B per octet per half), computes 8
// features (unpack fp16->fp32, add/relu/dot in fp32), 3-step shuffle-reduce.
__global__ void __launch_bounds__(256) k_edge4(const __half* __restrict__ pre,
                                               const int* __restrict__ row,
                                               const int* __restrict__ col,
                                               const float* __restrict__ w2,
                                               const float* __restrict__ b2,
                                               float* __restrict__ out){
    int t = threadIdx.x, w = t>>6, j = t&63;
    int wave = blockIdx.x*4 + w;
    const int NW = EBLOCKS*4;
    const int C = (NE + NW - 1)/NW;       // contiguous chunk per wave
    int e0 = wave*C, e1 = min(e0+C, NE);
    int p = j & 7;                        // part within octet
    int oc = j >> 3;                      // octet id 0..7
    float4 w2lo = *(const float4*)(w2 + 8*p);
    float4 w2hi = *(const float4*)(w2 + 8*p + 4);
    float b2v = b2[0];
    const unsigned short* ps = (const unsigned short*)pre;

    auto edot = [&](int r, int c)->float{
        uint4 ua = *(const uint4*)(ps + (size_t)r*128 + 8*p);        // A-half dwordx4 p
        uint4 ub = *(const uint4*)(ps + (size_t)c*128 + 64 + 8*p);   // B-half dwordx4 p
        const __half2* ah = (const __half2*)&ua;
        const __half2* bh = (const __half2*)&ub;
        float2 a0 = __half22float2(ah[0]), b0 = __half22float2(bh[0]);
        float2 a1 = __half22float2(ah[1]), b1 = __half22float2(bh[1]);
        float2 a2 = __half22float2(ah[2]), b2f = __half22float2(bh[2]);
        float2 a3 = __half22float2(ah[3]), b3 = __half22float2(bh[3]);
        float z;
        z  = fmaxf(a0.x+b0.x, 0.f)*w2lo.x + fmaxf(a0.y+b0.y, 0.f)*w2lo.y;
        z  = fmaf(fmaxf(a1.x+b1.x, 0.f), w2lo.z, z);
        z  = fmaf(fmaxf(a1.y+b1.y, 0.f), w2lo.w, z);
        z  = fmaf(fmaxf(a2.x+b2f.x,0.f), w2hi.x, z);
        z  = fmaf(fmaxf(a2.y+b2f.y,0.f), w2hi.y, z);
        z  = fmaf(fmaxf(a3.x+b3.x, 0.f), w2hi.z, z);
        z  = fmaf(fmaxf(a3.y+b3.y, 0.f), w2hi.w, z);
        return z;
    };

    int e = e0;
    for(; e + 16 <= e1; e += 16){         // 2 edges in flight per thread
        int ei = e + oc, ej = e + 8 + oc;
        int r0 = row[ei], c0 = col[ei];
        int r1 = row[ej], c1 = col[ej];
        float z0 = edot(r0, c0);
        float z1 = edot(r1, c1);
        z0 += __shfl_xor(z0, 1, 64); z1 += __shfl_xor(z1, 1, 64);
        z0 += __shfl_xor(z0, 2, 64); z1 += __shfl_xor(z1, 2, 64);
        z0 += __shfl_xor(z0, 4, 64); z1 += __shfl_xor(z1, 4, 64);
        if(p == 0){
            out[ei] = 1.f/(1.f+__expf(-(z0+b2v)));
            out[ej] = 1.f/(1.f+__expf(-(z1+b2v)));
        }
    }
    for(; e < e1; e += 8){                // predicated tail
        int ei = e + oc;
        bool valid = ei < e1;
        int eic = valid ? ei : (e1-1);
        int r0 = row[eic], c0 = col[eic];
        float z0 = edot(r0, c0);
        z0 += __shfl_xor(z0, 1, 64);
        z0 += __shfl_xor(z0, 2, 64);
        z0 += __shfl_xor(z0, 4, 64);
        if(p == 0 && valid) out[ei] = 1.f/(1.f+__expf(-(z0+b2v)));
    }
}

// ---------------- launch ----------------

extern "C" void kernel_launch(void* const* d_in, const int* in_sizes, int n_in,
                              void* d_out, int out_size, void* d_ws, size_t ws_size,
                              hipStream_t stream){
    const float* x   = (const float*)d_in[0];
    const int* ei    = (const int*)d_in[1];
    const int* row   = ei;
    const int* col   = ei + NE;
    const float* encW = (const float*)d_in[2],  *encB = (const float*)d_in[3];
    const float* encG = (const float*)d_in[4],  *encBe= (const float*)d_in[5];
    const float* encM = (const float*)d_in[6],  *encV = (const float*)d_in[7];
    const float* c1W  = (const float*)d_in[8],  *c1b  = (const float*)d_in[9];
    const float* c2W  = (const float*)d_in[10], *c2b  = (const float*)d_in[11];
    const float* ep1W = (const float*)d_in[12], *ep1b = (const float*)d_in[13];
    const float* epG  = (const float*)d_in[14], *epBe = (const float*)d_in[15];
    const float* epM  = (const float*)d_in[16], *epV  = (const float*)d_in[17];
    const float* ep2W = (const float*)d_in[18], *ep2b = (const float*)d_in[19];

    char* wsc = (char*)d_ws;
    size_t o = 0;
    auto alloc = [&](size_t bytes)->void*{
        void* p = wsc + o; o += (bytes + 255) & ~(size_t)255; return p;
    };
    int*    deg     = (int*)   alloc((size_t)NN*4);
    int*    starts  = (int*)   alloc((size_t)NN*4);
    int*    bsum    = (int*)   alloc(1024*4);
    int*    bcnt    = (int*)   alloc((size_t)NBUCK*4);
    int*    csr     = (int*)   alloc((size_t)NE*4);
    uint32* staged  = (uint32*)alloc((size_t)NBUCK*BCAP*4);   // 8.0 MB
    float*  dinv    = (float*) alloc((size_t)NN*4);
    float*  foldEnc = (float*) alloc(128*4);
    float*  foldPre = (float*) alloc(256*4);
    float*  bufA    = (float*) alloc((size_t)NN*64*4);        // fp32 h buffer (25.6 MB)
    __half* bufB    = (__half*)alloc((size_t)NN*64*2);        // fp16 hw' buffer (12.8 MB)
    // pre[N,128] fp16 (25.6 MB) aliases bufA (dead after conv2 gemv)
    __half* preh    = (__half*)bufA;
    // total ~54 MB of d_ws

    float* outp = (float*)d_out;               // [NN*64] node emb | [NE] edge preds
    float* node_out = outp;
    float* edge_out = outp + (size_t)NN*64;

    hipMemsetAsync(bcnt, 0, (size_t)NBUCK*4, stream);
    k_part <<<NCHUNK,  256, 0, stream>>>(row, col, bcnt, staged);
    k_hist <<<NBUCK,   256, 0, stream>>>(bcnt, staged, deg);
    k_bsum <<<NB_SCAN, 256, 0, stream>>>(deg, bsum);
    k_top  <<<1,       512, 0, stream>>>(bsum);
    k_scan <<<NB_SCAN, 256, 0, stream>>>(deg, bsum, starts, dinv);
    k_fill2<<<NBUCK,   256, 0, stream>>>(bcnt, staged, starts, csr);
    k_const<<<1, 64, 0, stream>>>(encB, encG, encBe, encM, encV,
                                  ep1b, epG, epBe, epM, epV, foldEnc, foldPre);

    // encoder: relu(bn(x @ encW + b)) -> fp32 bufA
    k_gemv<128,1,false,true,true,false,false><<<NB_SCAN, 256, 0, stream>>>(x, encW, foldEnc, nullptr, bufA);

    // conv1: hw' = (h @ W) * dinv, fp16 -> aggregate fp32
    k_gemv<64,1,false,false,false,true,true><<<NB_SCAN, 256, 0, stream>>>(bufA, c1W, nullptr, dinv, bufB);
    k_agg2 <<<NN/4, 256, 0, stream>>>(bufB, starts, deg, csr, dinv, c1b, bufA);

    // conv2
    k_gemv<64,1,false,false,false,true,true><<<NB_SCAN, 256, 0, stream>>>(bufA, c2W, nullptr, dinv, bufB);
    k_agg2 <<<NN/4, 256, 0, stream>>>(bufB, starts, deg, csr, dinv, c2b, node_out);

    // edge predictor precompute -> fp16 pre [A|B] interleaved
    k_gemv<64,2,true,true,false,true,false><<<NB_SCAN, 256, 0, stream>>>(node_out, ep1W, foldPre, nullptr, preh);

    // per-edge: sigmoid(sum relu(preA[r]+preB[c])*w2 + b2), octet-cooperative
    k_edge4<<<EBLOCKS, 256, 0, stream>>>(preh, row, col, ep2W, ep2b, edge_out);
}